// Round 10
// baseline (1567.746 us; speedup 1.0000x reference)
//
#include <hip/hip_runtime.h>

// Problem constants (fixed by the reference).
#define NGRID 262144      // N = 64^3 = 2^18
#define NNZ_C 1835008     // 7 * N
#define TP2   132         // LDS tile row stride (floats); 132*4 ≡ 0 mod 16
#define NSL   2048        // 128-wide n-slices
#define NBLK  1792        // 7 blocks/CU x 256 CU, co-resident by capacity

// Fixed-point scale for packed-pair atomic accumulation of yat.
#define FPSCALE   524288.0f          // 2^19
#define FPINV     (1.0f / 524288.0f)

// Loss closed form:  loss = mean_b( Stt - 2a*C2 + a^2*C3 ),  a = Sty/C1
//   C1=<yp,yat>  C2=<yt,yat>  C3=<yat,yat>  Stt=<yt,yt>  Sty=<yt,yp>
// LAWS (measured R0-R8):
//  * scatter: time ∝ line-RMW events; events=NNZ floor via 16-lane/edge
//    single-u64-atomic layout (163.8us flat / 166.0 grid-stride). FROZEN.
//  * C3 forces yat materialization -> scatter stays.
//  * never funnel >>1K atomics into few lines (R6: +80us).
//  * tail streaming is BW-perfect at the margin; ~65-95us of the 131us
//    tail is inter-kernel fixed overhead (launch/drain/ramp).
// R9 lesson: hipLaunchCooperativeKernel silently no-ops under the
// harness's graph capture (out stayed 0; absmax == ref). This round does
// the SAME fusion with a persistent-block software barrier: device-scope
// atomics + threadfence (cross-XCD safe), bounded spin (no hangs),
// regular launch (graph-capturable). 2 dispatches total.

// ---------------------------------------------------------------------------
// Software grid barrier: sense-reversal on (cnt, gen), agent scope.
// Read gen BEFORE incrementing cnt (ACQ_REL add pins the order).
// ---------------------------------------------------------------------------
__device__ __forceinline__ void gridbar(unsigned* cnt, unsigned* gen) {
    __syncthreads();
    if (threadIdx.x == 0) {
        __threadfence();                          // release our XCD's stores
        const unsigned g = __hip_atomic_load(gen, __ATOMIC_RELAXED,
                                             __HIP_MEMORY_SCOPE_AGENT);
        const unsigned a = __hip_atomic_fetch_add(cnt, 1u, __ATOMIC_ACQ_REL,
                                                  __HIP_MEMORY_SCOPE_AGENT);
        if (a == NBLK - 1) {
            __hip_atomic_store(cnt, 0u, __ATOMIC_RELAXED,
                               __HIP_MEMORY_SCOPE_AGENT);
            __hip_atomic_fetch_add(gen, 1u, __ATOMIC_RELEASE,
                                   __HIP_MEMORY_SCOPE_AGENT);
        } else {
            int spin = 0;
            while (__hip_atomic_load(gen, __ATOMIC_ACQUIRE,
                                     __HIP_MEMORY_SCOPE_AGENT) == g) {
                __builtin_amdgcn_s_sleep(4);
                if (++spin > 20000000) break;     // anti-hang bound
            }
        }
        __threadfence();                          // acquire: inv stale lines
    }
    __syncthreads();
}

// ---------------------------------------------------------------------------
// Init: zero the barrier words (workspace arrives poisoned). 1 block.
// ---------------------------------------------------------------------------
__global__ __launch_bounds__(64) void k_init(unsigned* __restrict__ bar) {
    if (threadIdx.x < 2) bar[threadIdx.x] = 0u;
}

// ---------------------------------------------------------------------------
// Mega-kernel: prep | scatter | post | reduce, separated by gridbar.
// All phase bodies are the R8-proven structures.
// ---------------------------------------------------------------------------
__global__ __launch_bounds__(256, 7) void k_mega(
        const float* __restrict__ yp, const float* __restrict__ yt,
        const float* __restrict__ Av, const int* __restrict__ Ar,
        const int* __restrict__ Ac,
        float* __restrict__ yp_t, unsigned long long* __restrict__ yat64,
        float* __restrict__ p2, float* __restrict__ pr2,
        unsigned* __restrict__ bar, float* __restrict__ out) {
    __shared__ __align__(16) float T[32 * TP2];      // 16.5 KB, all phases
    __shared__ float tot[160];
    __shared__ float lb[32];
    const int tid = threadIdx.x;
    const int blk = blockIdx.x;
    float* yat_f = (float*)yat64;

    // ---- Phase 1: prep — transpose yp -> yp_t (N,32), zero yat. ----
    for (int s = blk; s < NSL; s += NBLK) {
        const size_t n0 = (size_t)s * 128;
        #pragma unroll
        for (int q = 0; q < 4; ++q) {
            const int f = q * 256 + tid;         // float4 id, 0..1023
            const int row = f >> 5;              // 0..31
            const int off = (f & 31) * 4;        // 0..124
            const float4 a =
                *(const float4*)(yp + (size_t)row * NGRID + n0 + off);
            *(float4*)(&T[row * TP2 + off]) = a;
        }
        __syncthreads();
        float4* dst4 = (float4*)(yp_t + n0 * 32);
        float4* yz4  = (float4*)(yat_f + n0 * 32);
        #pragma unroll
        for (int q = 0; q < 4; ++q) {
            const int f = q * 256 + tid;         // 0..1023
            const int n = f >> 3;                // 0..127
            const int bb = 4 * (f & 7);
            float4 v;
            v.x = T[(bb + 0) * TP2 + n];
            v.y = T[(bb + 1) * TP2 + n];
            v.z = T[(bb + 2) * TP2 + n];
            v.w = T[(bb + 3) * TP2 + n];
            dst4[f] = v;
            yz4[f] = make_float4(0.f, 0.f, 0.f, 0.f);
        }
        __syncthreads();
    }
    gridbar(bar, bar + 1);

    // ---- Phase 2: scatter — FROZEN R4 memory pattern, grid-stride. ----
    {
        const int b2 = tid & 15;
        const size_t g0 = ((size_t)blk * 256 + tid) >> 4;   // 0..28671
        #pragma unroll 2
        for (int it = 0; it < NNZ_C / 28672; ++it) {        // 64 sweeps
            const size_t e = g0 + (size_t)it * 28672;
            const float v = Av[e];
            const int r = Ar[e];
            const int c = Ac[e];
            const float2 x2 = *(const float2*)(yp_t + (size_t)c * 32 + 2 * b2);
            const long long i0 = (long long)__float2int_rn(v * x2.x * FPSCALE);
            const long long i1 = (long long)__float2int_rn(v * x2.y * FPSCALE);
            atomicAdd(&yat64[(size_t)r * 16 + b2],
                      (unsigned long long)((i1 << 32) + i0));
        }
    }
    gridbar(bar, bar + 1);

    // ---- Phase 3: post — unpack+transpose yat tile, five dot products. ----
    for (int s = blk; s < NSL; s += NBLK) {
        const size_t n0 = (size_t)s * 128;
        const ulonglong2* y2 = (const ulonglong2*)(yat64 + n0 * 16);
        #pragma unroll
        for (int q = 0; q < 4; ++q) {
            const int f = q * 256 + tid;         // 0..1023 (ull2 index)
            const int n = f >> 3;                // 0..127
            const int b0 = 4 * (f & 7);
            const ulonglong2 pv = y2[f];
            // exact unpack: p = h*2^32 + lo (lo signed); h=(p+2^31)>>32
            const int lo0 = (int)(unsigned)pv.x;
            const int hi0 = (int)((pv.x + 0x80000000ULL) >> 32);
            const int lo1 = (int)(unsigned)pv.y;
            const int hi1 = (int)((pv.y + 0x80000000ULL) >> 32);
            T[(b0 + 0) * TP2 + n] = (float)lo0 * FPINV;
            T[(b0 + 1) * TP2 + n] = (float)hi0 * FPINV;
            T[(b0 + 2) * TP2 + n] = (float)lo1 * FPINV;
            T[(b0 + 3) * TP2 + n] = (float)hi1 * FPINV;
        }
        __syncthreads();
        const int b = tid >> 3, j = tid & 7;
        const float* ytb = yt + (size_t)b * NGRID + n0;
        const float* ypb = yp + (size_t)b * NGRID + n0;
        const float* Tb = &T[b * TP2];
        float c1 = 0.f, c2 = 0.f, c3 = 0.f, st = 0.f, sy = 0.f;
        #pragma unroll
        for (int ss = 0; ss < 4; ++ss) {
            const int n = 4 * j + 32 * ss;
            const float4 a = *(const float4*)(Tb + n);     // ds_read_b128
            const float4 t = *(const float4*)(ytb + n);
            const float4 p = *(const float4*)(ypb + n);
            c1 = fmaf(p.x, a.x, c1); c2 = fmaf(t.x, a.x, c2);
            c3 = fmaf(a.x, a.x, c3); st = fmaf(t.x, t.x, st);
            sy = fmaf(t.x, p.x, sy);
            c1 = fmaf(p.y, a.y, c1); c2 = fmaf(t.y, a.y, c2);
            c3 = fmaf(a.y, a.y, c3); st = fmaf(t.y, t.y, st);
            sy = fmaf(t.y, p.y, sy);
            c1 = fmaf(p.z, a.z, c1); c2 = fmaf(t.z, a.z, c2);
            c3 = fmaf(a.z, a.z, c3); st = fmaf(t.z, t.z, st);
            sy = fmaf(t.z, p.z, sy);
            c1 = fmaf(p.w, a.w, c1); c2 = fmaf(t.w, a.w, c2);
            c3 = fmaf(a.w, a.w, c3); st = fmaf(t.w, t.w, st);
            sy = fmaf(t.w, p.w, sy);
        }
        #pragma unroll
        for (int d = 4; d; d >>= 1) {            // reduce 8 lanes per b
            c1 += __shfl_down(c1, d, 8);
            c2 += __shfl_down(c2, d, 8);
            c3 += __shfl_down(c3, d, 8);
            st += __shfl_down(st, d, 8);
            sy += __shfl_down(sy, d, 8);
        }
        if (j == 0) {
            float* row = p2 + (size_t)s * 160;
            row[0 * 32 + b] = c1;
            row[1 * 32 + b] = c2;
            row[2 * 32 + b] = c3;
            row[3 * 32 + b] = st;
            row[4 * 32 + b] = sy;
        }
        __syncthreads();
    }
    gridbar(bar, bar + 1);

    // ---- Phase 4a: blocks 0..63 reduce p2 rows 32g..32g+31 -> pr2. ----
    if (blk < 64 && tid < 160) {
        float acc = 0.f;
        #pragma unroll
        for (int jj = 0; jj < 32; ++jj)
            acc += p2[(size_t)(blk * 32 + jj) * 160 + tid];
        pr2[blk * 160 + tid] = acc;
    }
    gridbar(bar, bar + 1);

    // ---- Phase 4b: block 0 reduces pr2 (64 rows) + closed-form loss. ----
    if (blk == 0) {
        if (tid < 160) {
            float acc = 0.f;
            #pragma unroll
            for (int jj = 0; jj < 64; ++jj) acc += pr2[jj * 160 + tid];
            tot[tid] = acc;
        }
        __syncthreads();
        if (tid < 32) {
            const float c1 = tot[0 + tid];
            const float c2 = tot[32 + tid];
            const float c3 = tot[64 + tid];
            const float stt = tot[96 + tid];
            const float sty = tot[128 + tid];
            const float a = sty / c1;
            lb[tid] = fmaf(a * a, c3, fmaf(-2.f * a, c2, stt));
        }
        __syncthreads();
        if (tid == 0) {
            float s = 0.f;
            #pragma unroll
            for (int i = 0; i < 32; ++i) s += lb[i];
            out[0] = s * (1.0f / 32.0f);
        }
    }
}

// ===========================================================================
extern "C" void kernel_launch(void* const* d_in, const int* in_sizes, int n_in,
                              void* d_out, int out_size, void* d_ws, size_t ws_size,
                              hipStream_t stream) {
    const float* yp = (const float*)d_in[0];   // y_pred (32, N)
    const float* yt = (const float*)d_in[1];   // y_true (32, N)
    const float* Av = (const float*)d_in[2];   // A_vals (NNZ)
    const int*   Ar = (const int*)d_in[3];     // A_rows (NNZ)
    const int*   Ac = (const int*)d_in[4];     // A_cols (NNZ)
    float* out = (float*)d_out;

    // Workspace: yp_t 33.6MB + yat64 33.6MB + p2 1.3MB + pr2 40KB + bar
    // ≈ 68.6 MB (round-0 proved >= 82.5 MB available).
    float* ws    = (float*)d_ws;
    float* yp_t  = ws;                              // N*32 f32
    float* yat_f = yp_t + (size_t)NGRID * 32;       // N*16 u64 (same bytes)
    unsigned long long* yat64 = (unsigned long long*)yat_f;
    float* p2    = yat_f + (size_t)NGRID * 32;      // 2048*160
    float* pr2   = p2 + (size_t)NSL * 160;          // 64*160
    unsigned* bar = (unsigned*)(pr2 + 64 * 160);    // 2 words

    k_init<<<1, 64, 0, stream>>>(bar);
    k_mega<<<NBLK, 256, 0, stream>>>(yp, yt, Av, Ar, Ac, yp_t, yat64,
                                     p2, pr2, bar, out);
}

// Round 11
// 1028.706 us; speedup vs baseline: 1.5240x; 1.5240x over previous
//
#include <hip/hip_runtime.h>

// Problem constants (fixed by the reference).
#define NGRID 262144      // N = 64^3 = 2^18
#define NNZ_C 1835008     // 7 * N
#define TP2   132         // LDS tile row stride (floats); 132*4 ≡ 0 mod 16
#define NSL   2048        // 128-wide n-slices

// Fixed-point scale for packed-pair atomic accumulation of yat.
#define FPSCALE   524288.0f          // 2^19
#define FPINV     (1.0f / 524288.0f)

// Loss closed form:  loss = mean_b( Stt - 2a*C2 + a^2*C3 ),  a = Sty/C1
//   C1=<yp,yat>  C2=<yt,yat>  C3=<yat,yat>  Stt=<yt,yt>  Sty=<yt,yp>
// LAWS (measured R0-R10):
//  * scatter: time ∝ line-RMW events (one wave atomic instr covering a
//    128B line = 1 event); events=NNZ floor; 11.2G events/s ceiling.
//    R4 layout = 163.8us flat / 166.0 grid-stride. Memory pattern FROZEN.
//  * C3 forces yat materialization -> scatter stays.
//  * single-line coherent ops cap at ~2.4 ops/ns: never funnel >>1K
//    atomics (R6: +80us) NOR >0.5 polls/ns of barrier spinning (R10:
//    4-cycle-interval polling from 1792 blocks -> 300us/barrier).
// This round: R10's fusion with the poll pressure fixed (backoff to
// s_sleep(96) ~= 2.6us interval -> 0.8 ops/ns) and 8 blocks/CU (2048
// blocks, occupancy-query-guarded) for perfect phase balance.

// ---------------------------------------------------------------------------
// Software grid barrier: sense-reversal (cnt, gen), agent scope, backoff.
// ---------------------------------------------------------------------------
__device__ __forceinline__ void gridbar(unsigned* cnt, unsigned* gen,
                                        unsigned nblk) {
    __syncthreads();
    if (threadIdx.x == 0) {
        __threadfence();                          // release our stores
        const unsigned g = __hip_atomic_load(gen, __ATOMIC_RELAXED,
                                             __HIP_MEMORY_SCOPE_AGENT);
        const unsigned a = __hip_atomic_fetch_add(cnt, 1u, __ATOMIC_ACQ_REL,
                                                  __HIP_MEMORY_SCOPE_AGENT);
        if (a == nblk - 1u) {
            __hip_atomic_store(cnt, 0u, __ATOMIC_RELAXED,
                               __HIP_MEMORY_SCOPE_AGENT);
            __hip_atomic_fetch_add(gen, 1u, __ATOMIC_RELEASE,
                                   __HIP_MEMORY_SCOPE_AGENT);
        } else {
            int i = 0;
            while (__hip_atomic_load(gen, __ATOMIC_ACQUIRE,
                                     __HIP_MEMORY_SCOPE_AGENT) == g) {
                if (i < 4) __builtin_amdgcn_s_sleep(8);    // ~0.2us
                else       __builtin_amdgcn_s_sleep(96);   // ~2.6us
                if (++i > 100000) break;          // anti-hang (~0.25s max)
            }
        }
        __threadfence();                          // acquire side
    }
    __syncthreads();
}

// ---------------------------------------------------------------------------
// Init: zero the barrier words (workspace arrives poisoned). 1 block.
// ---------------------------------------------------------------------------
__global__ __launch_bounds__(64) void k_init(unsigned* __restrict__ bar) {
    if (threadIdx.x < 2) bar[threadIdx.x] = 0u;
}

// ---------------------------------------------------------------------------
// Mega-kernel: prep | scatter | post | reduce, separated by gridbar.
// All phase bodies are the R8-proven structures (R10 verbatim).
// ---------------------------------------------------------------------------
__global__ __launch_bounds__(256, 8) void k_mega(
        const float* __restrict__ yp, const float* __restrict__ yt,
        const float* __restrict__ Av, const int* __restrict__ Ar,
        const int* __restrict__ Ac,
        float* __restrict__ yp_t, unsigned long long* __restrict__ yat64,
        float* __restrict__ p2, float* __restrict__ pr2,
        unsigned* __restrict__ bar, float* __restrict__ out,
        unsigned nblk) {
    __shared__ __align__(16) float T[32 * TP2];      // 16.5 KB, all phases
    __shared__ float tot[160];
    __shared__ float lb[32];
    const int tid = threadIdx.x;
    const int blk = blockIdx.x;
    float* yat_f = (float*)yat64;

    // ---- Phase 1: prep — transpose yp -> yp_t (N,32), zero yat. ----
    for (int s = blk; s < NSL; s += nblk) {
        const size_t n0 = (size_t)s * 128;
        #pragma unroll
        for (int q = 0; q < 4; ++q) {
            const int f = q * 256 + tid;         // float4 id, 0..1023
            const int row = f >> 5;              // 0..31
            const int off = (f & 31) * 4;        // 0..124
            const float4 a =
                *(const float4*)(yp + (size_t)row * NGRID + n0 + off);
            *(float4*)(&T[row * TP2 + off]) = a;
        }
        __syncthreads();
        float4* dst4 = (float4*)(yp_t + n0 * 32);
        float4* yz4  = (float4*)(yat_f + n0 * 32);
        #pragma unroll
        for (int q = 0; q < 4; ++q) {
            const int f = q * 256 + tid;         // 0..1023
            const int n = f >> 3;                // 0..127
            const int bb = 4 * (f & 7);
            float4 v;
            v.x = T[(bb + 0) * TP2 + n];
            v.y = T[(bb + 1) * TP2 + n];
            v.z = T[(bb + 2) * TP2 + n];
            v.w = T[(bb + 3) * TP2 + n];
            dst4[f] = v;
            yz4[f] = make_float4(0.f, 0.f, 0.f, 0.f);
        }
        __syncthreads();
    }
    gridbar(bar, bar + 1, nblk);

    // ---- Phase 2: scatter — FROZEN R4 memory pattern, grid-stride. ----
    {
        const int b2 = tid & 15;
        const size_t stride = (size_t)nblk * 16;          // 16-lane groups
        for (size_t e = ((size_t)blk * 256 + tid) >> 4; e < NNZ_C;
             e += stride) {
            const float v = Av[e];
            const int r = Ar[e];
            const int c = Ac[e];
            const float2 x2 = *(const float2*)(yp_t + (size_t)c * 32 + 2 * b2);
            const long long i0 = (long long)__float2int_rn(v * x2.x * FPSCALE);
            const long long i1 = (long long)__float2int_rn(v * x2.y * FPSCALE);
            atomicAdd(&yat64[(size_t)r * 16 + b2],
                      (unsigned long long)((i1 << 32) + i0));
        }
    }
    gridbar(bar, bar + 1, nblk);

    // ---- Phase 3: post — unpack+transpose yat tile, five dot products. ----
    for (int s = blk; s < NSL; s += nblk) {
        const size_t n0 = (size_t)s * 128;
        const ulonglong2* y2 = (const ulonglong2*)(yat64 + n0 * 16);
        #pragma unroll
        for (int q = 0; q < 4; ++q) {
            const int f = q * 256 + tid;         // 0..1023 (ull2 index)
            const int n = f >> 3;                // 0..127
            const int b0 = 4 * (f & 7);
            const ulonglong2 pv = y2[f];
            // exact unpack: p = h*2^32 + lo (lo signed); h=(p+2^31)>>32
            const int lo0 = (int)(unsigned)pv.x;
            const int hi0 = (int)((pv.x + 0x80000000ULL) >> 32);
            const int lo1 = (int)(unsigned)pv.y;
            const int hi1 = (int)((pv.y + 0x80000000ULL) >> 32);
            T[(b0 + 0) * TP2 + n] = (float)lo0 * FPINV;
            T[(b0 + 1) * TP2 + n] = (float)hi0 * FPINV;
            T[(b0 + 2) * TP2 + n] = (float)lo1 * FPINV;
            T[(b0 + 3) * TP2 + n] = (float)hi1 * FPINV;
        }
        __syncthreads();
        const int b = tid >> 3, j = tid & 7;
        const float* ytb = yt + (size_t)b * NGRID + n0;
        const float* ypb = yp + (size_t)b * NGRID + n0;
        const float* Tb = &T[b * TP2];
        float c1 = 0.f, c2 = 0.f, c3 = 0.f, st = 0.f, sy = 0.f;
        #pragma unroll
        for (int ss = 0; ss < 4; ++ss) {
            const int n = 4 * j + 32 * ss;
            const float4 a = *(const float4*)(Tb + n);     // ds_read_b128
            const float4 t = *(const float4*)(ytb + n);
            const float4 p = *(const float4*)(ypb + n);
            c1 = fmaf(p.x, a.x, c1); c2 = fmaf(t.x, a.x, c2);
            c3 = fmaf(a.x, a.x, c3); st = fmaf(t.x, t.x, st);
            sy = fmaf(t.x, p.x, sy);
            c1 = fmaf(p.y, a.y, c1); c2 = fmaf(t.y, a.y, c2);
            c3 = fmaf(a.y, a.y, c3); st = fmaf(t.y, t.y, st);
            sy = fmaf(t.y, p.y, sy);
            c1 = fmaf(p.z, a.z, c1); c2 = fmaf(t.z, a.z, c2);
            c3 = fmaf(a.z, a.z, c3); st = fmaf(t.z, t.z, st);
            sy = fmaf(t.z, p.z, sy);
            c1 = fmaf(p.w, a.w, c1); c2 = fmaf(t.w, a.w, c2);
            c3 = fmaf(a.w, a.w, c3); st = fmaf(t.w, t.w, st);
            sy = fmaf(t.w, p.w, sy);
        }
        #pragma unroll
        for (int d = 4; d; d >>= 1) {            // reduce 8 lanes per b
            c1 += __shfl_down(c1, d, 8);
            c2 += __shfl_down(c2, d, 8);
            c3 += __shfl_down(c3, d, 8);
            st += __shfl_down(st, d, 8);
            sy += __shfl_down(sy, d, 8);
        }
        if (j == 0) {
            float* row = p2 + (size_t)s * 160;
            row[0 * 32 + b] = c1;
            row[1 * 32 + b] = c2;
            row[2 * 32 + b] = c3;
            row[3 * 32 + b] = st;
            row[4 * 32 + b] = sy;
        }
        __syncthreads();
    }
    gridbar(bar, bar + 1, nblk);

    // ---- Phase 4a: blocks 0..63 reduce p2 rows 32g..32g+31 -> pr2. ----
    if (blk < 64 && tid < 160) {
        float acc = 0.f;
        #pragma unroll
        for (int jj = 0; jj < 32; ++jj)
            acc += p2[(size_t)(blk * 32 + jj) * 160 + tid];
        pr2[blk * 160 + tid] = acc;
    }
    gridbar(bar, bar + 1, nblk);

    // ---- Phase 4b: block 0 reduces pr2 (64 rows) + closed-form loss. ----
    if (blk == 0) {
        if (tid < 160) {
            float acc = 0.f;
            #pragma unroll
            for (int jj = 0; jj < 64; ++jj) acc += pr2[jj * 160 + tid];
            tot[tid] = acc;
        }
        __syncthreads();
        if (tid < 32) {
            const float c1 = tot[0 + tid];
            const float c2 = tot[32 + tid];
            const float c3 = tot[64 + tid];
            const float stt = tot[96 + tid];
            const float sty = tot[128 + tid];
            const float a = sty / c1;
            lb[tid] = fmaf(a * a, c3, fmaf(-2.f * a, c2, stt));
        }
        __syncthreads();
        if (tid == 0) {
            float s = 0.f;
            #pragma unroll
            for (int i = 0; i < 32; ++i) s += lb[i];
            out[0] = s * (1.0f / 32.0f);
        }
    }
}

// ===========================================================================
extern "C" void kernel_launch(void* const* d_in, const int* in_sizes, int n_in,
                              void* d_out, int out_size, void* d_ws, size_t ws_size,
                              hipStream_t stream) {
    const float* yp = (const float*)d_in[0];   // y_pred (32, N)
    const float* yt = (const float*)d_in[1];   // y_true (32, N)
    const float* Av = (const float*)d_in[2];   // A_vals (NNZ)
    const int*   Ar = (const int*)d_in[3];     // A_rows (NNZ)
    const int*   Ac = (const int*)d_in[4];     // A_cols (NNZ)
    float* out = (float*)d_out;

    // Workspace: yp_t 33.6MB + yat64 33.6MB + p2 1.3MB + pr2 40KB + bar
    // ≈ 68.6 MB (round-0 proved >= 82.5 MB available).
    float* ws    = (float*)d_ws;
    float* yp_t  = ws;                              // N*32 f32
    float* yat_f = yp_t + (size_t)NGRID * 32;       // N*16 u64 (same bytes)
    unsigned long long* yat64 = (unsigned long long*)yat_f;
    float* p2    = yat_f + (size_t)NGRID * 32;      // 2048*160
    float* pr2   = p2 + (size_t)NSL * 160;          // 64*160
    unsigned* bar = (unsigned*)(pr2 + 64 * 160);    // 2 words

    // Co-residency guard (host-side query, graph-capture safe): use the
    // occupancy the driver actually grants, capped at 8/CU; R10 proved 7.
    int maxb = 0;
    if (hipOccupancyMaxActiveBlocksPerMultiprocessor(&maxb, k_mega, 256, 0)
            != hipSuccess || maxb <= 0)
        maxb = 7;
    if (maxb > 8) maxb = 8;
    const unsigned nblk = (unsigned)maxb * 256u;

    k_init<<<1, 64, 0, stream>>>(bar);
    k_mega<<<nblk, 256, 0, stream>>>(yp, yt, Av, Ar, Ac, yp_t, yat64,
                                     p2, pr2, bar, out, nblk);
}

// Round 12
// 473.148 us; speedup vs baseline: 3.3134x; 2.1742x over previous
//
#include <hip/hip_runtime.h>

// Problem constants (fixed by the reference).
#define NGRID 262144      // N = 64^3 = 2^18
#define NNZ_C 1835008     // 7 * N
#define TP    260         // prep LDS row stride (floats); 260*4 ≡ 0 mod 16
#define NS    256         // k_post n-slice per block (R3/R8-proven shape)
#define TPAD  260         // k_post LDS row stride (floats), 16B-aligned rows

// Fixed-point scale for packed-pair atomic accumulation of yat.
// |value| bound before low-lane overflow: 2^31/2^19 = 4096 (typ |sum| < 50).
#define FPSCALE   524288.0f          // 2^19
#define FPINV     (1.0f / 524288.0f)

// Loss closed form:  loss = mean_b( Stt - 2a*C2 + a^2*C3 ),  a = Sty/C1
//   C1=<yp,yat>  C2=<yt,yat>  C3=<yat,yat>  Stt=<yt,yt>  Sty=<yt,yp>
// LAWS (measured R0-R11):
//  * scatter: time ∝ line-RMW events; events=NNZ floor via 16-lane/edge
//    single-u64-atomic layout (163.8us). Memory pattern FROZEN.
//  * C3 forces yat materialization -> scatter stays.
//  * single-line coherent-op funnels melt (R6 +80us); and NO cheap
//    software grid barrier exists on this part (R10/R11: ~350us/barrier
//    regardless of poll backoff) -> multi-kernel composition is final.
//  * tail streaming is BW-perfect at the margin (6.3 TB/s R0->R3).
// This round: R8 (296.1us, best) + last-block-done fusion of the two
// finish kernels into k_post (one atomicAdd per block on a done counter
// -- 1024 ops, 3 orders under the melt threshold; no polling). 3 launches.

// ---------------------------------------------------------------------------
// K1: yp transpose (R7-green tile construct) + zero yat; block 0 zeroes the
// done counter. grid = 1024 x 256.
// ---------------------------------------------------------------------------
__global__ __launch_bounds__(256) void k_prep(
        const float* __restrict__ yp, float* __restrict__ yp_t,
        float* __restrict__ yat_t, unsigned* __restrict__ done) {
    __shared__ __align__(16) float T[32 * TP];
    const int tid = threadIdx.x;
    if (blockIdx.x == 0 && tid == 0) *done = 0u;
    const int l = tid & 63, w = tid >> 6;
    const size_t n0 = (size_t)blockIdx.x * 256;
    #pragma unroll
    for (int s = 0; s < 8; ++s) {
        const int b = s * 4 + w;                 // unique (s,w) -> 0..31
        const float4 a = *(const float4*)(yp + (size_t)b * NGRID + n0 + 4 * l);
        *(float4*)(&T[b * TP + 4 * l]) = a;      // ds_write_b128, row b
    }
    __syncthreads();
    float4* dst4 = (float4*)(yp_t + n0 * 32);
    float4* yat4 = (float4*)(yat_t + n0 * 32);
    #pragma unroll
    for (int q = 0; q < 8; ++q) {
        const int f = q * 256 + tid;             // float4 index, 0..2047
        const int n = f >> 3;                    // 0..255 local n
        const int bb = 4 * (f & 7);              // base batch of this quad
        float4 v;
        v.x = T[(bb + 0) * TP + n];
        v.y = T[(bb + 1) * TP + n];
        v.z = T[(bb + 2) * TP + n];
        v.w = T[(bb + 3) * TP + n];
        dst4[f] = v;                             // coalesced 1 KB/wave
        yat4[f] = make_float4(0.f, 0.f, 0.f, 0.f);
    }
}

// ---------------------------------------------------------------------------
// K2: COO scatter — R4 verbatim (proven 163.8us; events=NNZ floor).
// thread -> (e=tid>>4, b2=tid&15): float2 gather from yp_t row c (16 lanes
// x 8B = full 128B line), fixed-point convert, ONE u64 atomic per lane pair
// (16 lanes x 8B = full 128B yat line in one instruction = one event).
// grid = NNZ*16/256 = 114688 blocks.
// ---------------------------------------------------------------------------
__global__ void k_scatter(const float* __restrict__ vals,
                          const int* __restrict__ rows,
                          const int* __restrict__ cols,
                          const float* __restrict__ yp_t,
                          unsigned long long* __restrict__ yat64) {
    const size_t tid = (size_t)blockIdx.x * blockDim.x + threadIdx.x;
    const int b2 = (int)(tid & 15);
    const size_t e = tid >> 4;
    const float v = vals[e];
    const int r = rows[e];
    const int c = cols[e];
    const float2 x2 = *(const float2*)(yp_t + (size_t)c * 32 + 2 * b2);
    const long long i0 = (long long)__float2int_rn(v * x2.x * FPSCALE);
    const long long i1 = (long long)__float2int_rn(v * x2.y * FPSCALE);
    atomicAdd(&yat64[(size_t)r * 16 + b2],
              (unsigned long long)((i1 << 32) + i0));
}

// ---------------------------------------------------------------------------
// K3: post-pass (R8 structure) + last-block-done finish fusion.
//   Phase A: load packed yat tile (256 x 16 u64, coalesced ulonglong2),
//            exact int64 unpack -> f32, LDS transposed T[b][n], TPAD=260.
//   Phase B: thread (b=tid>>3, j=tid&7): 8 float4 steps over n; yt/yp in
//            ORIGINAL (32,N) layout + ds_read_b128 from T; shfl-reduce the
//            8 lanes per batch; per-block partials to p2 (spread lines).
//   Finish:  __threadfence + one atomicAdd(done)/block; the 1024th block
//            reduces p2 (1024 x 160) and writes the closed-form loss.
//            (Release/acquire via threadfence + device-scope atomic —
//            the exact pattern R10/R11 proved correct cross-XCD.)
// ---------------------------------------------------------------------------
__global__ __launch_bounds__(256) void k_post(
        const unsigned long long* __restrict__ yat64,
        const float* __restrict__ yp, const float* __restrict__ yt,
        float* __restrict__ p2, unsigned* __restrict__ done,
        float* __restrict__ out) {
    __shared__ __align__(16) float T[32 * TPAD];     // 33.3 KB
    __shared__ float tot[160];
    __shared__ float lb[32];
    __shared__ unsigned s_last;
    const int tid = threadIdx.x;
    const int g = blockIdx.x;                    // 0..1023
    const size_t n0 = (size_t)g * NS;
    const ulonglong2* y2 = (const ulonglong2*)(yat64 + n0 * 16);
    #pragma unroll
    for (int q = 0; q < 8; ++q) {
        const int f = q * 256 + tid;             // 0..2047 (ull2 index)
        const int n = f >> 3;                    // 0..255
        const int b0 = 4 * (f & 7);
        const ulonglong2 pv = y2[f];
        // exact unpack: p = h*2^32 + lo (lo signed); h = (p + 2^31) >> 32
        const int lo0 = (int)(unsigned)pv.x;
        const int hi0 = (int)((pv.x + 0x80000000ULL) >> 32);
        const int lo1 = (int)(unsigned)pv.y;
        const int hi1 = (int)((pv.y + 0x80000000ULL) >> 32);
        T[(b0 + 0) * TPAD + n] = (float)lo0 * FPINV;
        T[(b0 + 1) * TPAD + n] = (float)hi0 * FPINV;
        T[(b0 + 2) * TPAD + n] = (float)lo1 * FPINV;
        T[(b0 + 3) * TPAD + n] = (float)hi1 * FPINV;
    }
    __syncthreads();
    const int b = tid >> 3, j = tid & 7;
    const float* ytb = yt + (size_t)b * NGRID + n0;
    const float* ypb = yp + (size_t)b * NGRID + n0;
    const float* Tb = &T[b * TPAD];
    float c1 = 0.f, c2 = 0.f, c3 = 0.f, st = 0.f, sy = 0.f;
    #pragma unroll
    for (int s = 0; s < NS / 32; ++s) {          // 8 steps
        const int n = 4 * j + 32 * s;
        const float4 a = *(const float4*)(Tb + n);     // ds_read_b128
        const float4 t = *(const float4*)(ytb + n);
        const float4 p = *(const float4*)(ypb + n);
        c1 = fmaf(p.x, a.x, c1); c2 = fmaf(t.x, a.x, c2);
        c3 = fmaf(a.x, a.x, c3); st = fmaf(t.x, t.x, st);
        sy = fmaf(t.x, p.x, sy);
        c1 = fmaf(p.y, a.y, c1); c2 = fmaf(t.y, a.y, c2);
        c3 = fmaf(a.y, a.y, c3); st = fmaf(t.y, t.y, st);
        sy = fmaf(t.y, p.y, sy);
        c1 = fmaf(p.z, a.z, c1); c2 = fmaf(t.z, a.z, c2);
        c3 = fmaf(a.z, a.z, c3); st = fmaf(t.z, t.z, st);
        sy = fmaf(t.z, p.z, sy);
        c1 = fmaf(p.w, a.w, c1); c2 = fmaf(t.w, a.w, c2);
        c3 = fmaf(a.w, a.w, c3); st = fmaf(t.w, t.w, st);
        sy = fmaf(t.w, p.w, sy);
    }
    #pragma unroll
    for (int d = 4; d; d >>= 1) {                // reduce 8 lanes per b
        c1 += __shfl_down(c1, d, 8);
        c2 += __shfl_down(c2, d, 8);
        c3 += __shfl_down(c3, d, 8);
        st += __shfl_down(st, d, 8);
        sy += __shfl_down(sy, d, 8);
    }
    if (j == 0) {
        float* row = p2 + (size_t)g * 160;
        row[0 * 32 + b] = c1;
        row[1 * 32 + b] = c2;
        row[2 * 32 + b] = c3;
        row[3 * 32 + b] = st;
        row[4 * 32 + b] = sy;
    }
    // ---- last-block-done finish ----
    __threadfence();                             // release p2 row
    __syncthreads();                             // all lanes' stores issued
    if (tid == 0) {
        const unsigned old = atomicAdd(done, 1u);    // device scope
        s_last = (old == 1023u) ? 1u : 0u;
    }
    __syncthreads();
    if (s_last) {
        __threadfence();                         // acquire all p2 rows
        if (tid < 160) {
            float acc = 0.f;
            for (int jj = 0; jj < 1024; ++jj)
                acc += p2[(size_t)jj * 160 + tid];
            tot[tid] = acc;
        }
        __syncthreads();
        if (tid < 32) {
            const float c1t = tot[0 + tid];
            const float c2t = tot[32 + tid];
            const float c3t = tot[64 + tid];
            const float stt = tot[96 + tid];
            const float sty = tot[128 + tid];
            const float a = sty / c1t;
            lb[tid] = fmaf(a * a, c3t, fmaf(-2.f * a, c2t, stt));
        }
        __syncthreads();
        if (tid == 0) {
            float s = 0.f;
            #pragma unroll
            for (int i = 0; i < 32; ++i) s += lb[i];
            out[0] = s * (1.0f / 32.0f);
        }
    }
}

// ===========================================================================
extern "C" void kernel_launch(void* const* d_in, const int* in_sizes, int n_in,
                              void* d_out, int out_size, void* d_ws, size_t ws_size,
                              hipStream_t stream) {
    const float* yp = (const float*)d_in[0];   // y_pred (32, N)
    const float* yt = (const float*)d_in[1];   // y_true (32, N)
    const float* Av = (const float*)d_in[2];   // A_vals (NNZ)
    const int*   Ar = (const int*)d_in[3];     // A_rows (NNZ)
    const int*   Ac = (const int*)d_in[4];     // A_cols (NNZ)
    float* out = (float*)d_out;

    // Workspace: yp_t 33.6MB + yat64 33.6MB + p2 640KB + done ≈ 68 MB
    // (round-0 proved >= 82.5 MB available).
    float* ws    = (float*)d_ws;
    float* yp_t  = ws;                              // N*32 f32
    float* yat_f = yp_t + (size_t)NGRID * 32;       // N*16 u64 (same bytes)
    unsigned long long* yat64 = (unsigned long long*)yat_f;
    float* p2    = yat_f + (size_t)NGRID * 32;      // 1024*160
    unsigned* done = (unsigned*)(p2 + 1024 * 160);  // 1 word

    k_prep<<<1024, 256, 0, stream>>>(yp, yp_t, yat_f, done);
    k_scatter<<<(NNZ_C * 16) / 256, 256, 0, stream>>>(Av, Ar, Ac, yp_t, yat64);
    k_post<<<1024, 256, 0, stream>>>(yat64, yp, yt, p2, done, out);
}